// Round 12
// baseline (137.661 us; speedup 1.0000x reference)
//
#include <hip/hip_runtime.h>
#include <hip/hip_bf16.h>

#define INC   256
#define HEADS 4
#define OUTC  64
#define NEG_SLOPE 0.2f
#define CAP   5120      // per-bucket edge capacity (lambda=4096, +16 sigma)
#define EPB_A 4096      // edges per pass-A block

typedef __attribute__((ext_vector_type(8))) short  fragA;  // 8 bf16 in 4 VGPRs
typedef __attribute__((ext_vector_type(4))) float  f32x4;

__device__ __forceinline__ float bf2f(unsigned short u) {
    union { unsigned int i; float f; } v; v.i = ((unsigned int)u) << 16; return v.f;
}
__device__ __forceinline__ unsigned short f2bf(float x) {
    __hip_bfloat16 b = __float2bfloat16(x);
    return *reinterpret_cast<unsigned short*>(&b);
}

// ---------------- Wt = bf16(W^T) [256 n][256 k]; also zero bucket tails ----------------
__global__ __launch_bounds__(256) void wt_zero_kernel(const float* __restrict__ W,
                                                      unsigned short* __restrict__ Wt,
                                                      int* __restrict__ btail, int nbuck)
{
    int idx = blockIdx.x * 256 + threadIdx.x;   // 0..65535
    int k = idx >> 8, c = idx & 255;
    Wt[c * 256 + k] = f2bf(W[k * 256 + c]);
    if (idx < nbuck) btail[idx] = 0;
}

// ---------------- heterogeneous: pass-A bucket scatter (blocks < nbA) + GEMM ----------------
__global__ __launch_bounds__(256, 2) void gemm_passA(
    const float* __restrict__ A,            // [M,256] f32
    const unsigned short* __restrict__ Wt,  // [256 n][256 k] bf16
    const float* __restrict__ att_src,      // [4,64]
    const float* __restrict__ att_dst,      // [4,64]
    unsigned short* __restrict__ H2,        // [M,256] bf16
    float* __restrict__ a_srcO,             // [M,4]
    float* __restrict__ a_dstO,             // [M,4]
    int M,
    const int* __restrict__ src, const int* __restrict__ dst,
    int* __restrict__ btail,                // [nbuck]
    int2* __restrict__ bucketbuf,           // [nbuck*CAP]
    int E, int nbA)
{
    __shared__ __align__(16) unsigned short As[64 * 256];   // 32 KB (pass A reuses)
    const int tid = threadIdx.x;

    if ((int)blockIdx.x < nbA) {
        // ---------------- pass A: bin edges by dst>>8 ----------------
        char* sm = (char*)As;
        int* lhist = (int*)sm;            // 256 ints
        int* lrankc = (int*)(sm + 1024);  // 256 ints
        int* gbase  = (int*)(sm + 2048);  // 256 ints
        lhist[tid] = 0; lrankc[tid] = 0;
        __syncthreads();
        int e0 = blockIdx.x * EPB_A;
        int e1 = e0 + EPB_A; if (e1 > E) e1 = E;
        for (int e = e0 + tid; e < e1; e += 256)
            atomicAdd(&lhist[dst[e] >> 8], 1);
        __syncthreads();
        {
            int c = lhist[tid];
            gbase[tid] = (c > 0) ? atomicAdd(&btail[tid], c) : 0;
        }
        __syncthreads();
        for (int e = e0 + tid; e < e1; e += 256) {
            int s = src[e], d = dst[e];
            int b = d >> 8;
            int r = atomicAdd(&lrankc[b], 1);
            bucketbuf[(size_t)b * CAP + gbase[b] + r] = make_int2(s, d);
        }
        return;
    }

    // ---------------- GEMM blocks ----------------
    const int lane = tid & 63;
    const int wave = tid >> 6;
    const int row0 = ((int)blockIdx.x - nbA) * 64;
    const int g   = lane >> 4;
    const int r16 = lane & 15;

    fragA b[4][8];
    {
        const unsigned short* wp = Wt + (size_t)(wave * 64) * 256;
        #pragma unroll
        for (int nn = 0; nn < 4; ++nn)
            #pragma unroll
            for (int kk = 0; kk < 8; ++kk)
                b[nn][kk] = *(const fragA*)(wp + (size_t)(nn * 16 + r16) * 256 + kk * 32 + g * 8);
    }

    #pragma unroll
    for (int i = 0; i < 16; ++i) {
        int f   = i * 256 + tid;
        int row = f >> 6;
        int q   = f & 63;
        int gr  = row0 + row;
        float4 v = (gr < M) ? *(const float4*)(A + (size_t)gr * INC + q * 4)
                            : make_float4(0.f, 0.f, 0.f, 0.f);
        ushort4 u;
        u.x = f2bf(v.x); u.y = f2bf(v.y); u.z = f2bf(v.z); u.w = f2bf(v.w);
        int byte = (row << 9) + (q << 3);
        byte ^= (row & 7) << 4;
        *(ushort4*)((char*)As + byte) = u;
    }
    __syncthreads();

    f32x4 acc[4][4] = {};
    #pragma unroll
    for (int kk = 0; kk < 8; ++kk) {
        fragA a[4];
        #pragma unroll
        for (int m = 0; m < 4; ++m) {
            int row  = m * 16 + r16;
            int byte = (row << 9) + ((kk * 32 + g * 8) << 1);
            byte ^= (row & 7) << 4;
            a[m] = *(const fragA*)((const char*)As + byte);
        }
        #pragma unroll
        for (int m = 0; m < 4; ++m)
            #pragma unroll
            for (int nn = 0; nn < 4; ++nn)
                acc[m][nn] = __builtin_amdgcn_mfma_f32_16x16x32_bf16(
                    a[m], b[nn][kk], acc[m][nn], 0, 0, 0);
    }

    #pragma unroll
    for (int m = 0; m < 4; ++m) {
        #pragma unroll
        for (int nn = 0; nn < 4; ++nn) {
            int gcol = wave * 64 + nn * 16 + r16;
            #pragma unroll
            for (int r = 0; r < 4; ++r) {
                int grow = row0 + m * 16 + g * 4 + r;
                if (grow < M)
                    H2[(size_t)grow * (HEADS * OUTC) + gcol] = f2bf(acc[m][nn][r]);
            }
        }
    }

    {
        float as_att[4], ad_att[4];
        #pragma unroll
        for (int nn = 0; nn < 4; ++nn) {
            as_att[nn] = att_src[wave * 64 + nn * 16 + r16];
            ad_att[nn] = att_dst[wave * 64 + nn * 16 + r16];
        }
        float sv[4][4], dv[4][4];
        #pragma unroll
        for (int m = 0; m < 4; ++m)
            #pragma unroll
            for (int r = 0; r < 4; ++r) {
                float s = 0.f, d = 0.f;
                #pragma unroll
                for (int nn = 0; nn < 4; ++nn) {
                    s = fmaf(acc[m][nn][r], as_att[nn], s);
                    d = fmaf(acc[m][nn][r], ad_att[nn], d);
                }
                sv[m][r] = s; dv[m][r] = d;
            }
        #pragma unroll
        for (int off = 1; off < 16; off <<= 1) {
            #pragma unroll
            for (int m = 0; m < 4; ++m)
                #pragma unroll
                for (int r = 0; r < 4; ++r) {
                    sv[m][r] += __shfl_xor(sv[m][r], off, 64);
                    dv[m][r] += __shfl_xor(dv[m][r], off, 64);
                }
        }
        #pragma unroll
        for (int m = 0; m < 4; ++m)
            #pragma unroll
            for (int r = 0; r < 4; ++r) {
                if (r16 == m * 4 + r) {
                    int grow = row0 + m * 16 + g * 4 + r;
                    if (grow < M) {
                        a_srcO[(size_t)grow * HEADS + wave] = sv[m][r];
                        a_dstO[(size_t)grow * HEADS + wave] = dv[m][r];
                    }
                }
            }
    }
}

// ---------------- pass B: in-bucket counting sort -> CSR esrc + offsets ----------------
__global__ __launch_bounds__(256) void passB_kernel(const int2* __restrict__ bucketbuf,
                                                    const int* __restrict__ btail,
                                                    int* __restrict__ offsets,
                                                    int* __restrict__ esrc,
                                                    int N, int E)
{
    __shared__ int lcnt[256];
    __shared__ int red[256];
    __shared__ unsigned short lrank[CAP];
    const int b = blockIdx.x, t = threadIdx.x;

    int s0 = 0;
    for (int j = t; j < b; j += 256) s0 += btail[j];
    red[t] = s0;
    __syncthreads();
    for (int off = 128; off > 0; off >>= 1) {
        if (t < off) red[t] += red[t + off];
        __syncthreads();
    }
    const int baseg = red[0];
    const int cnt = btail[b];
    __syncthreads();

    lcnt[t] = 0;
    __syncthreads();
    const int2* bb = bucketbuf + (size_t)b * CAP;
    for (int i = t; i < cnt; i += 256)
        lrank[i] = (unsigned short)atomicAdd(&lcnt[bb[i].y & 255], 1);
    __syncthreads();

    int v = lcnt[t];
    red[t] = v;
    __syncthreads();
    for (int off = 1; off < 256; off <<= 1) {
        int x = (t >= off) ? red[t - off] : 0;
        __syncthreads();
        red[t] += x;
        __syncthreads();
    }
    int excl = red[t] - v;
    lcnt[t] = excl;
    int node = b * 256 + t;
    if (node < N) offsets[node] = baseg + excl;
    if (b == 0 && t == 0) offsets[N] = E;
    __syncthreads();

    for (int i = t; i < cnt; i += 256) {
        int2 sd = bb[i];
        int slot = baseg + lcnt[sd.y & 255] + lrank[i];
        esrc[slot] = sd.x;
    }
}

// ---------------- fused aggregation: 2-stage software-pipelined 8-batches ----------------
// wave per node; lane = head*16 + cg; inline exp. Stage k+1's gathers + k+2's esrc
// before computing batch k, so L2/L3 gather latency hides under the VALU phase.
// Register sets are arrays with fully-unrolled constant-index loops (stay in VGPRs).
__global__ __launch_bounds__(128) void fused_agg_kernel(
    const unsigned short* __restrict__ h2,      // [N,256] bf16
    const float* __restrict__ a_src,            // [N,4]
    const float* __restrict__ a_dst,            // [N,4]
    const int*   __restrict__ offsets,          // [N+1]
    const int*   __restrict__ esrc,             // [E]
    const float* __restrict__ bias,             // [64]
    float*       __restrict__ out,              // [N,64]
    int n)
{
    int i    = (int)((blockIdx.x * blockDim.x + threadIdx.x) >> 6);
    int lane = threadIdx.x & 63;
    if (i >= n) return;
    const int h  = lane >> 4;
    const int cg = lane & 15;

    const float ad = a_dst[(size_t)i * HEADS + h];
    const unsigned short* h2p = h2 + lane * 4;

    float acc0, acc1, acc2, acc3, l;
    {   // self-loop
        float as = a_src[(size_t)i * HEADS + h];
        float e = as + ad; e = e > 0.f ? e : NEG_SLOPE * e;
        float p = __expf(e);
        ushort4 v = *(const ushort4*)(h2p + (size_t)i * 256);
        l = p;
        acc0 = p * bf2f(v.x);
        acc1 = p * bf2f(v.y);
        acc2 = p * bf2f(v.z);
        acc3 = p * bf2f(v.w);
    }

#define EDGE_BODY(S, AS)                                                     \
    {                                                                        \
        float e_ = (AS) + ad; e_ = e_ > 0.f ? e_ : NEG_SLOPE * e_;           \
        float p_ = __expf(e_);                                               \
        ushort4 v_ = *(const ushort4*)(h2p + (size_t)(S) * 256);             \
        l += p_;                                                             \
        acc0 = fmaf(p_, bf2f(v_.x), acc0);                                   \
        acc1 = fmaf(p_, bf2f(v_.y), acc1);                                   \
        acc2 = fmaf(p_, bf2f(v_.z), acc2);                                   \
        acc3 = fmaf(p_, bf2f(v_.w), acc3);                                   \
    }

    int beg = offsets[i], end = offsets[i + 1];
    int j = beg;
    // align to 4 for int4 esrc loads
    for (; j < end && (j & 3); ++j) {
        int s = esrc[j];
        float as = a_src[(size_t)s * HEADS + h];
        EDGE_BODY(s, as);
    }

    // pipelined 8-batches: two register sets A/B (arrays, static-indexed)
    int     sA[8], sB[8];
    float   pA[8], pB[8];
    ushort4 vA[8], vB[8];

#define STAGE_E(SS, JJ)                                                      \
    if ((JJ) + 7 < end) {                                                    \
        int4 ea_ = *(const int4*)(esrc + (JJ));                              \
        int4 eb_ = *(const int4*)(esrc + (JJ) + 4);                          \
        s##SS[0] = ea_.x; s##SS[1] = ea_.y; s##SS[2] = ea_.z; s##SS[3] = ea_.w; \
        s##SS[4] = eb_.x; s##SS[5] = eb_.y; s##SS[6] = eb_.z; s##SS[7] = eb_.w; \
    } else {                                                                 \
        _Pragma("unroll")                                                    \
        for (int q_ = 0; q_ < 8; ++q_) s##SS[q_] = i;                        \
    }

#define STAGE_G(SS)                                                          \
    _Pragma("unroll")                                                        \
    for (int q_ = 0; q_ < 8; ++q_) {                                         \
        p##SS[q_] = a_src[(size_t)s##SS[q_] * HEADS + h];                    \
        v##SS[q_] = *(const ushort4*)(h2p + (size_t)s##SS[q_] * 256);        \
    }

#define COMPUTE(SS)                                                          \
    _Pragma("unroll")                                                        \
    for (int q_ = 0; q_ < 8; ++q_) {                                         \
        float e_ = p##SS[q_] + ad; e_ = e_ > 0.f ? e_ : NEG_SLOPE * e_;      \
        float pp_ = __expf(e_);                                              \
        l += pp_;                                                            \
        acc0 = fmaf(pp_, bf2f(v##SS[q_].x), acc0);                           \
        acc1 = fmaf(pp_, bf2f(v##SS[q_].y), acc1);                           \
        acc2 = fmaf(pp_, bf2f(v##SS[q_].z), acc2);                           \
        acc3 = fmaf(pp_, bf2f(v##SS[q_].w), acc3);                           \
    }

    int nb = (end - j) >> 3;
    if (nb >= 2) {
        STAGE_E(A, j);
        STAGE_E(B, j + 8);
        STAGE_G(A);
        int k = 0;
        for (; k + 2 < nb; k += 2) {
            STAGE_G(B);
            STAGE_E(A, j + (k + 2) * 8);
            COMPUTE(A);
            STAGE_G(A);
            STAGE_E(B, j + (k + 3) * 8);
            COMPUTE(B);
        }
        if (nb - k == 2) {
            STAGE_G(B);
            COMPUTE(A);
            COMPUTE(B);
        } else {    // nb - k == 1
            COMPUTE(A);
        }
        j += nb * 8;
    } else if (nb == 1) {
        STAGE_E(A, j);
        STAGE_G(A);
        COMPUTE(A);
        j += 8;
    }

    // batch of 4
    if (j + 3 < end) {
        int4 ea = *(const int4*)(esrc + j);
        float as0 = a_src[(size_t)ea.x * HEADS + h];
        float as1 = a_src[(size_t)ea.y * HEADS + h];
        float as2 = a_src[(size_t)ea.z * HEADS + h];
        float as3 = a_src[(size_t)ea.w * HEADS + h];
        EDGE_BODY(ea.x, as0);
        EDGE_BODY(ea.y, as1);
        EDGE_BODY(ea.z, as2);
        EDGE_BODY(ea.w, as3);
        j += 4;
    }
    for (; j < end; ++j) {
        int s = esrc[j];
        float as = a_src[(size_t)s * HEADS + h];
        EDGE_BODY(s, as);
    }
#undef EDGE_BODY
#undef STAGE_E
#undef STAGE_G
#undef COMPUTE

    float inv = 1.f / (l + 1e-16f);
    float r0 = acc0 * inv, r1 = acc1 * inv, r2 = acc2 * inv, r3 = acc3 * inv;

    r0 += __shfl_xor(r0, 16, 64); r0 += __shfl_xor(r0, 32, 64);
    r1 += __shfl_xor(r1, 16, 64); r1 += __shfl_xor(r1, 32, 64);
    r2 += __shfl_xor(r2, 16, 64); r2 += __shfl_xor(r2, 32, 64);
    r3 += __shfl_xor(r3, 16, 64); r3 += __shfl_xor(r3, 32, 64);

    if (lane < 16) {
        float4 b4 = *(const float4*)(bias + cg * 4);
        float4 o;
        o.x = 0.25f * r0 + b4.x;
        o.y = 0.25f * r1 + b4.y;
        o.z = 0.25f * r2 + b4.z;
        o.w = 0.25f * r3 + b4.w;
        *(float4*)(out + (size_t)i * OUTC + cg * 4) = o;
    }
}

extern "C" void kernel_launch(void* const* d_in, const int* in_sizes, int n_in,
                              void* d_out, int out_size, void* d_ws, size_t ws_size,
                              hipStream_t stream)
{
    (void)n_in; (void)out_size; (void)ws_size;
    const float* x       = (const float*)d_in[0];
    const int*   edge    = (const int*)d_in[1];
    const float* W       = (const float*)d_in[2];
    const float* att_src = (const float*)d_in[3];
    const float* att_dst = (const float*)d_in[4];
    const float* bias    = (const float*)d_in[5];
    float* out = (float*)d_out;

    const int N = in_sizes[0] / INC;
    const int E = in_sizes[1] / 2;
    const int* srcA = edge;
    const int* dstA = edge + E;
    const int nbuck = (N + 255) / 256;          // 196
    const int nbA   = (E + EPB_A - 1) / EPB_A;  // 196

    char* ws = (char*)d_ws;
    unsigned short* h2 = (unsigned short*)ws; ws += (size_t)N * (HEADS * OUTC) * sizeof(unsigned short);
    unsigned short* Wt = (unsigned short*)ws; ws += (size_t)256 * 256 * sizeof(unsigned short);
    float* a_src  = (float*)ws; ws += (size_t)N * HEADS * sizeof(float);
    float* a_dst  = (float*)ws; ws += (size_t)N * HEADS * sizeof(float);
    int* offsets  = (int*)ws;   ws += (size_t)(N + 1) * sizeof(int) + 12;
    int* btail    = (int*)ws;   ws += (size_t)256 * sizeof(int);
    int2* bucketbuf = (int2*)ws; ws += (size_t)nbuck * CAP * sizeof(int2);
    int* esrc     = (int*)ws;   ws += (size_t)E * sizeof(int);

    wt_zero_kernel<<<256, 256, 0, stream>>>(W, Wt, btail, nbuck);

    gemm_passA<<<nbA + (N + 63) / 64, 256, 0, stream>>>(
        x, Wt, att_src, att_dst, h2, a_src, a_dst, N,
        srcA, dstA, btail, bucketbuf, E, nbA);

    passB_kernel<<<nbuck, 256, 0, stream>>>(bucketbuf, btail, offsets, esrc, N, E);

    fused_agg_kernel<<<(N + 1) / 2, 128, 0, stream>>>(h2, a_src, a_dst, offsets, esrc,
                                                      bias, out, N);
}